// Round 6
// baseline (77.267 us; speedup 1.0000x reference)
//
#include <hip/hip_runtime.h>
#include <hip/hip_bf16.h>

// KAN conv: out[b,o,h,w] = sum_{j,k,l,m} phi(x[b,j,h+k,w+l])[m] * coeff[o,j,k,l,m]
// phi = uniform cubic B-spline basis (8 bases, knots = linspace(0,1,12)).
// R6: R5 chassis (block=(b,h), 992 blocks, K-split waves, 32x32x16 MFMA) but
// phi staging is WAVE-PRIVATE (wave kh stages only its own j-pair region) ->
// ZERO barriers in the main loop; phi-eval VALU + ds_writes interleaved into
// the tap/MFMA stream (k-plane rewritten only after its taps consumed).
// v_cvt_pk_bf16_f32 packs; all LDS addrs = 1 base VGPR + imm offsets.

typedef short v8s __attribute__((ext_vector_type(8)));
typedef float v4f __attribute__((ext_vector_type(4)));
typedef float v16f __attribute__((ext_vector_type(16)));
typedef unsigned long long u64;
typedef u64 v2u64 __attribute__((ext_vector_type(2)));

#define B_N   16
#define CIN   64
#define COUT  64
#define H_IN  64
#define W_IN  64
#define NB    8
#define HO    62
#define WO    62
#define JC    8
#define NCH   8

__device__ __forceinline__ ushort f2bf(float f) {
    uint xu = __float_as_uint(f);
    return (ushort)((xu + 0x7fffu + ((xu >> 16) & 1u)) >> 16);
}

__device__ __forceinline__ uint cvtpk(float a, float b) {
    // packed RNE f32->bf16 pair (no builtin on gfx950; T12 recipe)
    uint r;
    asm("v_cvt_pk_bf16_f32 %0, %1, %2" : "=v"(r) : "v"(a), "v"(b));
    return r;
}

// bt layout: [jc(8)][tap(9)][jp(4)][o(64)][g2(2)][m(8)] bf16, 576 KB.
// j_global = jc*8 + jp*2 + g2; tap = k*3+l.
__global__ void prep_coeff_kernel(const float* __restrict__ coeff, ushort* __restrict__ bt) {
    int n = blockIdx.x * 256 + threadIdx.x;   // 294912 total
    if (n >= 294912) return;
    int m  = n & 7;
    int g2 = (n >> 3) & 1;
    int o  = (n >> 4) & 63;
    int jp = (n >> 10) & 3;
    int q  = n >> 12;          // 0..71
    int tap = q % 9;
    int jc  = q / 9;
    int j = jc * 8 + jp * 2 + g2;
    bt[n] = f2bf(coeff[((o * CIN + j) * 9 + tap) * 8 + m]);
}

#define MFMA32(a, b, c) __builtin_amdgcn_mfma_f32_32x32x16_bf16((a), (b), (c), 0, 0, 0)
#define MFMA16(a, b, c) __builtin_amdgcn_mfma_f32_16x16x32_bf16((a), (b), (c), 0, 0, 0)

__global__ __launch_bounds__(256, 4) void kan_conv_ks2(
        const float* __restrict__ x, const ushort* __restrict__ cb,
        float* __restrict__ out) {
    const int h    = blockIdx.x;      // 0..61
    const int b    = blockIdx.y;
    const int tid  = threadIdx.x;
    const int lane = tid & 63;
    const int kh   = tid >> 6;        // wave id = K-split (jp = kh)
    const int l31  = lane & 31;
    const int g2   = lane >> 5;

    // 24 KB phi (4 wave-private 6 KB regions [k(3)][j2(2)][w(64)][m(8)]) + reduce
    __shared__ __align__(16) char smraw[32768];

    char* wrB = smraw + kh * 6144 + lane * 16;              // write base (+e*1024)
    const char* rdB = smraw + kh * 6144 + g2 * 1024 + l31 * 16;  // read base (+k*2048+wf*512+lt*16)

    v16f acc[2][2];
    acc[0][0] = (v16f)(0.f); acc[0][1] = (v16f)(0.f);
    acc[1][0] = (v16f)(0.f); acc[1][1] = (v16f)(0.f);

    float xr[2][6];
    // elem e = k*2 + j2 : x[b, jc*8 + kh*2 + j2, h+k, w=lane]
    const float* xb = x + ((size_t)(b * CIN) * H_IN + h) * W_IN + lane;
    const int jx = kh * 2;

    auto XL = [&](int dst, int jc) {
        #pragma unroll
        for (int e = 0; e < 6; ++e) {
            int k = e >> 1, j2 = e & 1;
            xr[dst][e] = xb[(size_t)(jc * 8 + jx + j2) * (H_IN * W_IN) + k * W_IN];
        }
    };
    auto PW = [&](int src, int e) {   // phi-eval + single b128 write (region slot e)
        float s_ = xr[src][e] * 11.0f;
        int i0 = (int)s_;
        i0 = i0 < 0 ? 0 : (i0 > 10 ? 10 : i0);
        float u  = s_ - (float)i0;
        float um = 1.0f - u;
        float u2 = u * u, u3 = u2 * u;
        const float inv6 = 1.0f / 6.0f;
        float n0 = um * um * um * inv6;
        float n1 = (3.0f * u3 - 6.0f * u2 + 4.0f) * inv6;
        float n2 = (-3.0f * u3 + 3.0f * u2 + 3.0f * u + 1.0f) * inv6;
        float n3 = u3 * inv6;
        u64 V = (u64)cvtpk(n0, n1) | ((u64)cvtpk(n2, n3) << 32);
        int bi = i0 - 3;   // first active basis index, in [-3, 7]
        u64 lo = bi < 0 ? (V >> (uint)(-16 * bi))
               : bi < 4 ? (V << (uint)(16 * bi)) : 0ull;
        u64 hi = bi <= 0 ? 0ull
               : bi < 4 ? (V >> (uint)(64 - 16 * bi))
               : (V << (uint)(16 * bi - 64));
        v2u64 pk; pk[0] = lo; pk[1] = hi;
        *reinterpret_cast<v2u64*>(wrB + e * 1024) = pk;
    };
    auto TAP = [&](const char* pAc, int k, int lt, int tap) {
        v8s b0 = *reinterpret_cast<const v8s*>(rdB + k * 2048 + lt * 16);
        v8s b1 = *reinterpret_cast<const v8s*>(rdB + k * 2048 + 512 + lt * 16);
        v8s a0 = *reinterpret_cast<const v8s*>(pAc + tap * 8192);
        v8s a1 = *reinterpret_cast<const v8s*>(pAc + tap * 8192 + 1024);
        acc[0][0] = MFMA32(a0, b0, acc[0][0]);
        acc[0][1] = MFMA32(a0, b1, acc[0][1]);
        acc[1][0] = MFMA32(a1, b0, acc[1][0]);
        acc[1][1] = MFMA32(a1, b1, acc[1][1]);
    };

    const char* pA = (const char*)cb + (size_t)(kh * 128 + l31 * 2 + g2) * 16;

    // prologue: phi(c0) written by this wave only (in-order DS => no barrier)
    XL(0, 0);
    #pragma unroll
    for (int e = 0; e < 6; ++e) PW(0, e);
    XL(1, 1);

    // main loop: NO barriers. Chunk jc: GEMM(jc) || phi-write(jc+1) || xload(jc+2)
    auto CHUNK = [&](int jc, int cur, int nxt) {
        const char* pAc = pA + (size_t)jc * 73728;
        TAP(pAc, 0, 0, 0);
        TAP(pAc, 0, 1, 1);
        if (jc + 2 < NCH) XL(nxt, jc + 2);
        TAP(pAc, 0, 2, 2);
        if (jc + 1 < NCH) { PW(cur, 0); PW(cur, 1); }   // k=0 plane done
        TAP(pAc, 1, 0, 3);
        TAP(pAc, 1, 1, 4);
        TAP(pAc, 1, 2, 5);
        if (jc + 1 < NCH) { PW(cur, 2); PW(cur, 3); }   // k=1 plane done
        TAP(pAc, 2, 0, 6);
        TAP(pAc, 2, 1, 7);
        TAP(pAc, 2, 2, 8);
        if (jc + 1 < NCH) { PW(cur, 4); PW(cur, 5); }   // k=2 plane done
    };
    for (int jj = 0; jj < 4; ++jj) {
        CHUNK(2 * jj,     1, 0);   // even: phi src bank 1, xload into 0
        CHUNK(2 * jj + 1, 0, 1);   // odd : phi src bank 0, xload into 1
    }

    // ---- epilogue: parallel 2-round cross-wave K-reduce ----
    auto wr_full = [&](int off) {
        #pragma unroll
        for (int t = 0; t < 4; ++t)
            #pragma unroll
            for (int q = 0; q < 4; ++q) {
                v4f v;
                #pragma unroll
                for (int z = 0; z < 4; ++z) v[z] = acc[t >> 1][t & 1][q * 4 + z];
                *reinterpret_cast<v4f*>(smraw + off + (t * 4 + q) * 1024 + lane * 16) = v;
            }
    };
    auto add_full = [&](int off) {
        #pragma unroll
        for (int t = 0; t < 4; ++t)
            #pragma unroll
            for (int q = 0; q < 4; ++q) {
                v4f v = *reinterpret_cast<const v4f*>(smraw + off + (t * 4 + q) * 1024 + lane * 16);
                #pragma unroll
                for (int z = 0; z < 4; ++z) acc[t >> 1][t & 1][q * 4 + z] += v[z];
            }
    };
    auto wr_half = [&](int ot, int off) {
        #pragma unroll
        for (int wf = 0; wf < 2; ++wf)
            #pragma unroll
            for (int q = 0; q < 4; ++q) {
                v4f v;
                #pragma unroll
                for (int z = 0; z < 4; ++z) v[z] = acc[ot][wf][q * 4 + z];
                *reinterpret_cast<v4f*>(smraw + off + (wf * 4 + q) * 1024 + lane * 16) = v;
            }
    };
    auto add_half = [&](int ot, int off) {
        #pragma unroll
        for (int wf = 0; wf < 2; ++wf)
            #pragma unroll
            for (int q = 0; q < 4; ++q) {
                v4f v = *reinterpret_cast<const v4f*>(smraw + off + (wf * 4 + q) * 1024 + lane * 16);
                #pragma unroll
                for (int z = 0; z < 4; ++z) acc[ot][wf][q * 4 + z] += v[z];
            }
    };

    __syncthreads();                       // all GEMM reads of phi done
    if (kh == 1) wr_full(0);
    if (kh == 3) wr_full(16384);
    __syncthreads();
    if (kh == 0) add_full(0);              // w0: sum of j 0..3
    if (kh == 2) add_full(16384);          // w2: sum of j 4..7
    __syncthreads();
    if (kh == 2) wr_half(0, 0);            // w2's o-low  -> for w0
    if (kh == 0) wr_half(1, 8192);         // w0's o-high -> for w2
    __syncthreads();
    if (kh == 0) add_half(0, 0);           // w0 owns o 0..31
    if (kh == 2) add_half(1, 8192);        // w2 owns o 32..63

    if (kh == 0 || kh == 2) {
        const int ot = kh >> 1;
        #pragma unroll
        for (int wf = 0; wf < 2; ++wf) {
            int w = wf * 32 + l31;
            if (w < WO) {
                #pragma unroll
                for (int reg = 0; reg < 16; ++reg) {
                    int o = ot * 32 + (reg & 3) + 8 * (reg >> 2) + 4 * g2;
                    out[((b * COUT + o) * HO + h) * WO + w] = acc[ot][wf][reg];
                }
            }
        }
    }
}

// ---- fallback (ws too small for bt): R2-proven kernel, coeff from f32 ----
__global__ __launch_bounds__(256, 4) void kan_conv_fb(
        const float* __restrict__ x, const float* __restrict__ coeff_f,
        float* __restrict__ out) {
    const int h    = blockIdx.x;
    const int b    = blockIdx.y;
    const int tid  = threadIdx.x;
    const int lane = tid & 63;
    const int wv   = tid >> 6;
    const int g    = lane >> 4;
    const int l15  = lane & 15;
    const int obase = (wv >> 1) << 5;
    const int wbase = (wv & 1) << 5;

    __shared__ __align__(16) ushort phi_lds[3 * JC * W_IN * NB];
    __shared__ uint lut[72];
    if (tid < 72) {
        int tap = tid;
        int j  = tap / 9;
        int r9 = tap - j * 9;
        int kt = r9 / 3;
        int lt = r9 - kt * 3;
        lut[tap] = (uint)(((kt * JC + j) * W_IN) * NB) | ((uint)lt << 16)
                 | ((uint)j << 20) | ((uint)r9 << 24);
    }
    v4f acc00 = {0.f, 0.f, 0.f, 0.f};
    v4f acc01 = acc00, acc10 = acc00, acc11 = acc00;
    const int aoff = obase + l15;
    float xv[6];
    #pragma unroll
    for (int it = 0; it < 6; ++it) {
        int n = it * 256 + tid;
        xv[it] = x[((b * CIN + ((n >> 6) & 7)) * H_IN + (h + (n >> 9))) * W_IN + (n & 63)];
    }
    for (int jc = 0; jc < NCH; ++jc) {
        #pragma unroll
        for (int it = 0; it < 6; ++it) {
            int n = it * 256 + tid;
            float s  = xv[it] * 11.0f;
            int i0 = (int)s;
            i0 = i0 < 0 ? 0 : (i0 > 10 ? 10 : i0);
            float u  = s - (float)i0;
            float um = 1.0f - u;
            float u2 = u * u, u3 = u2 * u;
            const float inv6 = 1.0f / 6.0f;
            float n0 = um * um * um * inv6;
            float n1 = (3.0f * u3 - 6.0f * u2 + 4.0f) * inv6;
            float n2 = (-3.0f * u3 + 3.0f * u2 + 3.0f * u + 1.0f) * inv6;
            float n3 = u3 * inv6;
            u64 V = (u64)f2bf(n0) | ((u64)f2bf(n1) << 16)
                  | ((u64)f2bf(n2) << 32) | ((u64)f2bf(n3) << 48);
            int bi = i0 - 3;
            u64 lo = bi < 0 ? (V >> (uint)(-16 * bi))
                   : bi < 4 ? (V << (uint)(16 * bi)) : 0ull;
            u64 hi = bi <= 0 ? 0ull
                   : bi < 4 ? (V >> (uint)(64 - 16 * bi))
                   : (V << (uint)(16 * bi - 64));
            v2u64 pk; pk[0] = lo; pk[1] = hi;
            *reinterpret_cast<v2u64*>(&phi_lds[n << 3]) = pk;
        }
        if (jc + 1 < NCH) {
            int j0n = (jc + 1) * JC;
            #pragma unroll
            for (int it = 0; it < 6; ++it) {
                int n = it * 256 + tid;
                xv[it] = x[((b * CIN + j0n + ((n >> 6) & 7)) * H_IN + (h + (n >> 9))) * W_IN + (n & 63)];
            }
        }
        __syncthreads();
        const int j0 = jc * JC;
        #pragma unroll 6
        for (int kk = 0; kk < 18; ++kk) {
            int tap = (kk << 2) + g;
            uint e = lut[tap];
            int philoc = (int)(e & 0xffffu);
            int lt     = (int)((e >> 16) & 3u);
            int w0 = wbase + l15 + lt;
            int w1 = w0 + 16;
            w0 = w0 < 63 ? w0 : 63;
            w1 = w1 < 63 ? w1 : 63;
            v8s pb0 = *reinterpret_cast<const v8s*>(&phi_lds[philoc + (w0 << 3)]);
            v8s pb1 = *reinterpret_cast<const v8s*>(&phi_lds[philoc + (w1 << 3)]);
            int j  = (int)((e >> 20) & 15u);
            int r9 = (int)((e >> 24) & 15u);
            const float* cf = coeff_f + (((aoff * CIN + (j0 + j)) * 9 + r9) << 3);
            v8s pa0, pa1;
            #pragma unroll
            for (int z = 0; z < 8; ++z) pa0[z] = (short)f2bf(cf[z]);
            const float* cf2 = cf + (CIN * 9 * NB * 16);
            #pragma unroll
            for (int z = 0; z < 8; ++z) pa1[z] = (short)f2bf(cf2[z]);
            acc00 = MFMA16(pa0, pb0, acc00);
            acc01 = MFMA16(pa0, pb1, acc01);
            acc10 = MFMA16(pa1, pb0, acc10);
            acc11 = MFMA16(pa1, pb1, acc11);
        }
        __syncthreads();
    }
    const int wc0 = wbase + l15;
    const int wc1 = wc0 + 16;
    #pragma unroll
    for (int i = 0; i < 2; ++i) {
        v4f a0 = (i == 0) ? acc00 : acc10;
        v4f a1 = (i == 0) ? acc01 : acc11;
        int o = obase + i * 16 + (g << 2);
        #pragma unroll
        for (int r = 0; r < 4; ++r) {
            int off = ((b * COUT + o + r) * HO + h) * WO;
            if (wc0 < WO) out[off + wc0] = a0[r];
            if (wc1 < WO) out[off + wc1] = a1[r];
        }
    }
}

extern "C" void kernel_launch(void* const* d_in, const int* in_sizes, int n_in,
                              void* d_out, int out_size, void* d_ws, size_t ws_size,
                              hipStream_t stream) {
    const float* x     = (const float*)d_in[0];
    const float* coeff = (const float*)d_in[1];
    float* out = (float*)d_out;

    const size_t bt_bytes = (size_t)294912 * 2;  // 576 KB
    if (ws_size >= bt_bytes) {
        ushort* bt = (ushort*)d_ws;
        prep_coeff_kernel<<<(294912 + 255) / 256, 256, 0, stream>>>(coeff, bt);
        kan_conv_ks2<<<dim3(HO, B_N), 256, 0, stream>>>(x, bt, out);
    } else {
        kan_conv_fb<<<dim3(HO, B_N), 256, 0, stream>>>(x, coeff, out);
    }
}

// Round 7
// 53.441 us; speedup vs baseline: 1.4458x; 1.4458x over previous
//
#include <hip/hip_runtime.h>
#include <hip/hip_bf16.h>

// KAN conv: out[b,o,h,w] = sum_{j,k,l,m} phi(x[b,j,h+k,w+l])[m] * coeff[o,j,k,l,m]
// phi = uniform cubic B-spline basis (8 bases, knots = linspace(0,1,12)).
// R7 = R6 (barrier-free wave-private phi staging, K-split waves, 32x32x16 MFMA)
// with rule#20 fixes: ALL register-array indices compile-time static
// (epilogue per-kh static macros; xr0/xr1 named ping-pong; PW by-value).
// R6's 204MB WRITE_SIZE was acc spilling to scratch from runtime `ot` index.

typedef short v8s __attribute__((ext_vector_type(8)));
typedef float v4f __attribute__((ext_vector_type(4)));
typedef float v16f __attribute__((ext_vector_type(16)));
typedef unsigned long long u64;
typedef u64 v2u64 __attribute__((ext_vector_type(2)));

#define B_N   16
#define CIN   64
#define COUT  64
#define H_IN  64
#define W_IN  64
#define NB    8
#define HO    62
#define WO    62
#define JC    8
#define NCH   8

__device__ __forceinline__ ushort f2bf(float f) {
    uint xu = __float_as_uint(f);
    return (ushort)((xu + 0x7fffu + ((xu >> 16) & 1u)) >> 16);
}

__device__ __forceinline__ uint cvtpk(float a, float b) {
    uint r;
    asm("v_cvt_pk_bf16_f32 %0, %1, %2" : "=v"(r) : "v"(a), "v"(b));
    return r;
}

// bt layout: [jc(8)][tap(9)][jp(4)][o(64)][g2(2)][m(8)] bf16, 576 KB.
__global__ void prep_coeff_kernel(const float* __restrict__ coeff, ushort* __restrict__ bt) {
    int n = blockIdx.x * 256 + threadIdx.x;
    if (n >= 294912) return;
    int m  = n & 7;
    int g2 = (n >> 3) & 1;
    int o  = (n >> 4) & 63;
    int jp = (n >> 10) & 3;
    int q  = n >> 12;
    int tap = q % 9;
    int jc  = q / 9;
    int j = jc * 8 + jp * 2 + g2;
    bt[n] = f2bf(coeff[((o * CIN + j) * 9 + tap) * 8 + m]);
}

#define MFMA32(a, b, c) __builtin_amdgcn_mfma_f32_32x32x16_bf16((a), (b), (c), 0, 0, 0)
#define MFMA16(a, b, c) __builtin_amdgcn_mfma_f32_16x16x32_bf16((a), (b), (c), 0, 0, 0)

__global__ __launch_bounds__(256, 4) void kan_conv_ks3(
        const float* __restrict__ x, const ushort* __restrict__ cb,
        float* __restrict__ out) {
    const int h    = blockIdx.x;      // 0..61
    const int b    = blockIdx.y;
    const int tid  = threadIdx.x;
    const int lane = tid & 63;
    const int kh   = tid >> 6;        // wave id = K-split (jp = kh)
    const int l31  = lane & 31;
    const int g2   = lane >> 5;

    // 24 KB phi (4 wave-private 6 KB regions [k(3)][j2(2)][w(64)][m(8)]) + reduce
    __shared__ __align__(16) char smraw[32768];

    char* wrB = smraw + kh * 6144 + lane * 16;                   // + e*1024
    const char* rdB = smraw + kh * 6144 + g2 * 1024 + l31 * 16;  // + k*2048 + wf*512 + lt*16

    v16f acc[2][2];
    acc[0][0] = (v16f)(0.f); acc[0][1] = (v16f)(0.f);
    acc[1][0] = (v16f)(0.f); acc[1][1] = (v16f)(0.f);

    float xr0[6], xr1[6];
    const float* xb = x + ((size_t)(b * CIN) * H_IN + h) * W_IN + lane;
    const int jx = kh * 2;

// elem e = k*2 + j2 : x[b, jc*8 + kh*2 + j2, h+k, w=lane]  (static e -> registers)
#define XL(dst, jcn) { \
    _Pragma("unroll") \
    for (int e = 0; e < 6; ++e) \
        dst[e] = xb[(size_t)((jcn) * 8 + jx + (e & 1)) * (H_IN * W_IN) + (e >> 1) * W_IN]; \
    }

    auto PW = [&](float xval, int e) {   // phi-eval + single b128 write (slot e)
        float s_ = xval * 11.0f;
        int i0 = (int)s_;
        i0 = i0 < 0 ? 0 : (i0 > 10 ? 10 : i0);
        float u  = s_ - (float)i0;
        float um = 1.0f - u;
        float u2 = u * u, u3 = u2 * u;
        const float inv6 = 1.0f / 6.0f;
        float n0 = um * um * um * inv6;
        float n1 = (3.0f * u3 - 6.0f * u2 + 4.0f) * inv6;
        float n2 = (-3.0f * u3 + 3.0f * u2 + 3.0f * u + 1.0f) * inv6;
        float n3 = u3 * inv6;
        u64 V = (u64)cvtpk(n0, n1) | ((u64)cvtpk(n2, n3) << 32);
        int bi = i0 - 3;   // first active basis index, in [-3, 7]
        u64 lo = bi < 0 ? (V >> (uint)(-16 * bi))
               : bi < 4 ? (V << (uint)(16 * bi)) : 0ull;
        u64 hi = bi <= 0 ? 0ull
               : bi < 4 ? (V >> (uint)(64 - 16 * bi))
               : (V << (uint)(16 * bi - 64));
        v2u64 pk; pk[0] = lo; pk[1] = hi;
        *reinterpret_cast<v2u64*>(wrB + e * 1024) = pk;
    };
    auto TAP = [&](const char* pAc, int k, int lt, int tap) {
        v8s b0 = *reinterpret_cast<const v8s*>(rdB + k * 2048 + lt * 16);
        v8s b1 = *reinterpret_cast<const v8s*>(rdB + k * 2048 + 512 + lt * 16);
        v8s a0 = *reinterpret_cast<const v8s*>(pAc + tap * 8192);
        v8s a1 = *reinterpret_cast<const v8s*>(pAc + tap * 8192 + 1024);
        acc[0][0] = MFMA32(a0, b0, acc[0][0]);
        acc[0][1] = MFMA32(a0, b1, acc[0][1]);
        acc[1][0] = MFMA32(a1, b0, acc[1][0]);
        acc[1][1] = MFMA32(a1, b1, acc[1][1]);
    };

    const char* pA = (const char*)cb + (size_t)(kh * 128 + l31 * 2 + g2) * 16;

    // prologue: phi(c0) written by this wave only (in-order DS => no barrier)
    XL(xr0, 0);
    PW(xr0[0], 0); PW(xr0[1], 1); PW(xr0[2], 2);
    PW(xr0[3], 3); PW(xr0[4], 4); PW(xr0[5], 5);
    XL(xr1, 1);

// Chunk jc: GEMM(jc) || phi-write(jc+1 from CUR) || xload(jc+2 into NXT)
#define CHUNK(jc, CUR, NXT) { \
    const char* pAc = pA + (size_t)(jc) * 73728; \
    TAP(pAc, 0, 0, 0); \
    TAP(pAc, 0, 1, 1); \
    if ((jc) + 2 < NCH) XL(NXT, (jc) + 2); \
    TAP(pAc, 0, 2, 2); \
    if ((jc) + 1 < NCH) { PW(CUR[0], 0); PW(CUR[1], 1); } \
    TAP(pAc, 1, 0, 3); \
    TAP(pAc, 1, 1, 4); \
    TAP(pAc, 1, 2, 5); \
    if ((jc) + 1 < NCH) { PW(CUR[2], 2); PW(CUR[3], 3); } \
    TAP(pAc, 2, 0, 6); \
    TAP(pAc, 2, 1, 7); \
    TAP(pAc, 2, 2, 8); \
    if ((jc) + 1 < NCH) { PW(CUR[4], 4); PW(CUR[5], 5); } \
    }

    for (int jj = 0; jj < 4; ++jj) {
        CHUNK(2 * jj,     xr1, xr0);
        CHUNK(2 * jj + 1, xr0, xr1);
    }

    // ---- epilogue: parallel 2-round cross-wave K-reduce, ALL static indices ----
#define WR_FULL(off) { \
    _Pragma("unroll") \
    for (int t = 0; t < 4; ++t) { \
        _Pragma("unroll") \
        for (int q = 0; q < 4; ++q) { \
            v4f v; \
            _Pragma("unroll") \
            for (int z = 0; z < 4; ++z) v[z] = acc[t >> 1][t & 1][q * 4 + z]; \
            *reinterpret_cast<v4f*>(smraw + (off) + (t * 4 + q) * 1024 + lane * 16) = v; \
        } } }
#define ADD_FULL(off) { \
    _Pragma("unroll") \
    for (int t = 0; t < 4; ++t) { \
        _Pragma("unroll") \
        for (int q = 0; q < 4; ++q) { \
            v4f v = *reinterpret_cast<const v4f*>(smraw + (off) + (t * 4 + q) * 1024 + lane * 16); \
            _Pragma("unroll") \
            for (int z = 0; z < 4; ++z) acc[t >> 1][t & 1][q * 4 + z] += v[z]; \
        } } }
#define WR_HALF(OT, off) { \
    _Pragma("unroll") \
    for (int wf = 0; wf < 2; ++wf) { \
        _Pragma("unroll") \
        for (int q = 0; q < 4; ++q) { \
            v4f v; \
            _Pragma("unroll") \
            for (int z = 0; z < 4; ++z) v[z] = acc[OT][wf][q * 4 + z]; \
            *reinterpret_cast<v4f*>(smraw + (off) + (wf * 4 + q) * 1024 + lane * 16) = v; \
        } } }
#define ADD_HALF(OT, off) { \
    _Pragma("unroll") \
    for (int wf = 0; wf < 2; ++wf) { \
        _Pragma("unroll") \
        for (int q = 0; q < 4; ++q) { \
            v4f v = *reinterpret_cast<const v4f*>(smraw + (off) + (wf * 4 + q) * 1024 + lane * 16); \
            _Pragma("unroll") \
            for (int z = 0; z < 4; ++z) acc[OT][wf][q * 4 + z] += v[z]; \
        } } }
#define STORE_HALF(OT) { \
    _Pragma("unroll") \
    for (int wf = 0; wf < 2; ++wf) { \
        int w = wf * 32 + l31; \
        if (w < WO) { \
            _Pragma("unroll") \
            for (int reg = 0; reg < 16; ++reg) { \
                int o = (OT) * 32 + (reg & 3) + 8 * (reg >> 2) + 4 * g2; \
                out[((b * COUT + o) * HO + h) * WO + w] = acc[OT][wf][reg]; \
            } } } }

    __syncthreads();                       // all GEMM reads of phi done
    if (kh == 1) WR_FULL(0);
    if (kh == 3) WR_FULL(16384);
    __syncthreads();
    if (kh == 0) ADD_FULL(0);              // w0: sum of j 0..3
    if (kh == 2) ADD_FULL(16384);          // w2: sum of j 4..7
    __syncthreads();
    if (kh == 2) WR_HALF(0, 0);            // w2's o-low  -> for w0
    if (kh == 0) WR_HALF(1, 8192);         // w0's o-high -> for w2
    __syncthreads();
    if (kh == 0) { ADD_HALF(0, 0);    STORE_HALF(0); }   // w0 owns o 0..31
    if (kh == 2) { ADD_HALF(1, 8192); STORE_HALF(1); }   // w2 owns o 32..63
}

// ---- fallback (ws too small for bt): R2-proven kernel, coeff from f32 ----
__global__ __launch_bounds__(256, 4) void kan_conv_fb(
        const float* __restrict__ x, const float* __restrict__ coeff_f,
        float* __restrict__ out) {
    const int h    = blockIdx.x;
    const int b    = blockIdx.y;
    const int tid  = threadIdx.x;
    const int lane = tid & 63;
    const int wv   = tid >> 6;
    const int g    = lane >> 4;
    const int l15  = lane & 15;
    const int obase = (wv >> 1) << 5;
    const int wbase = (wv & 1) << 5;

    __shared__ __align__(16) ushort phi_lds[3 * JC * W_IN * NB];
    __shared__ uint lut[72];
    if (tid < 72) {
        int tap = tid;
        int j  = tap / 9;
        int r9 = tap - j * 9;
        int kt = r9 / 3;
        int lt = r9 - kt * 3;
        lut[tap] = (uint)(((kt * JC + j) * W_IN) * NB) | ((uint)lt << 16)
                 | ((uint)j << 20) | ((uint)r9 << 24);
    }
    v4f acc00 = {0.f, 0.f, 0.f, 0.f};
    v4f acc01 = acc00, acc10 = acc00, acc11 = acc00;
    const int aoff = obase + l15;
    float xv[6];
    #pragma unroll
    for (int it = 0; it < 6; ++it) {
        int n = it * 256 + tid;
        xv[it] = x[((b * CIN + ((n >> 6) & 7)) * H_IN + (h + (n >> 9))) * W_IN + (n & 63)];
    }
    for (int jc = 0; jc < NCH; ++jc) {
        #pragma unroll
        for (int it = 0; it < 6; ++it) {
            int n = it * 256 + tid;
            float s  = xv[it] * 11.0f;
            int i0 = (int)s;
            i0 = i0 < 0 ? 0 : (i0 > 10 ? 10 : i0);
            float u  = s - (float)i0;
            float um = 1.0f - u;
            float u2 = u * u, u3 = u2 * u;
            const float inv6 = 1.0f / 6.0f;
            float n0 = um * um * um * inv6;
            float n1 = (3.0f * u3 - 6.0f * u2 + 4.0f) * inv6;
            float n2 = (-3.0f * u3 + 3.0f * u2 + 3.0f * u + 1.0f) * inv6;
            float n3 = u3 * inv6;
            u64 V = (u64)f2bf(n0) | ((u64)f2bf(n1) << 16)
                  | ((u64)f2bf(n2) << 32) | ((u64)f2bf(n3) << 48);
            int bi = i0 - 3;
            u64 lo = bi < 0 ? (V >> (uint)(-16 * bi))
                   : bi < 4 ? (V << (uint)(16 * bi)) : 0ull;
            u64 hi = bi <= 0 ? 0ull
                   : bi < 4 ? (V >> (uint)(64 - 16 * bi))
                   : (V << (uint)(16 * bi - 64));
            v2u64 pk; pk[0] = lo; pk[1] = hi;
            *reinterpret_cast<v2u64*>(&phi_lds[n << 3]) = pk;
        }
        if (jc + 1 < NCH) {
            int j0n = (jc + 1) * JC;
            #pragma unroll
            for (int it = 0; it < 6; ++it) {
                int n = it * 256 + tid;
                xv[it] = x[((b * CIN + j0n + ((n >> 6) & 7)) * H_IN + (h + (n >> 9))) * W_IN + (n & 63)];
            }
        }
        __syncthreads();
        const int j0 = jc * JC;
        #pragma unroll 6
        for (int kk = 0; kk < 18; ++kk) {
            int tap = (kk << 2) + g;
            uint e = lut[tap];
            int philoc = (int)(e & 0xffffu);
            int lt     = (int)((e >> 16) & 3u);
            int w0 = wbase + l15 + lt;
            int w1 = w0 + 16;
            w0 = w0 < 63 ? w0 : 63;
            w1 = w1 < 63 ? w1 : 63;
            v8s pb0 = *reinterpret_cast<const v8s*>(&phi_lds[philoc + (w0 << 3)]);
            v8s pb1 = *reinterpret_cast<const v8s*>(&phi_lds[philoc + (w1 << 3)]);
            int j  = (int)((e >> 20) & 15u);
            int r9 = (int)((e >> 24) & 15u);
            const float* cf = coeff_f + (((aoff * CIN + (j0 + j)) * 9 + r9) << 3);
            v8s pa0, pa1;
            #pragma unroll
            for (int z = 0; z < 8; ++z) pa0[z] = (short)f2bf(cf[z]);
            const float* cf2 = cf + (CIN * 9 * NB * 16);
            #pragma unroll
            for (int z = 0; z < 8; ++z) pa1[z] = (short)f2bf(cf2[z]);
            acc00 = MFMA16(pa0, pb0, acc00);
            acc01 = MFMA16(pa0, pb1, acc01);
            acc10 = MFMA16(pa1, pb0, acc10);
            acc11 = MFMA16(pa1, pb1, acc11);
        }
        __syncthreads();
    }
    const int wc0 = wbase + l15;
    const int wc1 = wc0 + 16;
    #pragma unroll
    for (int i = 0; i < 2; ++i) {
        v4f a0 = (i == 0) ? acc00 : acc10;
        v4f a1 = (i == 0) ? acc01 : acc11;
        int o = obase + i * 16 + (g << 2);
        #pragma unroll
        for (int r = 0; r < 4; ++r) {
            int off = ((b * COUT + o + r) * HO + h) * WO;
            if (wc0 < WO) out[off + wc0] = a0[r];
            if (wc1 < WO) out[off + wc1] = a1[r];
        }
    }
}

extern "C" void kernel_launch(void* const* d_in, const int* in_sizes, int n_in,
                              void* d_out, int out_size, void* d_ws, size_t ws_size,
                              hipStream_t stream) {
    const float* x     = (const float*)d_in[0];
    const float* coeff = (const float*)d_in[1];
    float* out = (float*)d_out;

    const size_t bt_bytes = (size_t)294912 * 2;  // 576 KB
    if (ws_size >= bt_bytes) {
        ushort* bt = (ushort*)d_ws;
        prep_coeff_kernel<<<(294912 + 255) / 256, 256, 0, stream>>>(coeff, bt);
        kan_conv_ks3<<<dim3(HO, B_N), 256, 0, stream>>>(x, bt, out);
    } else {
        kan_conv_fb<<<dim3(HO, B_N), 256, 0, stream>>>(x, coeff, out);
    }
}